// Round 7
// baseline (66.817 us; speedup 1.0000x reference)
//
#include <hip/hip_runtime.h>

// SequentialSparsemax: (8, 16, 262144) f32.
// pass1: sparsemax over 16 instruments at every (b, t).
// pass2: sparsemax over each 64-sample frame per (b, inst).
//
// One wave = one (16 inst x 64 time) frame; 32768 waves.
//   pass1: lane = time column; serial sort16 over insts (A[16] + z[16]).
//   pass2: each row (inst) owned by a LANE-QUAD (4 lanes x 16 regs).
//          18/21 bitonic stages are in-register; 3 cross-lane via
//          ds_swizzle xor1/xor2 with per-lane-uniform keepmax masks.
//          tau: in-lane prefix + 2-swizzle quad scan + max-identity
//          tau = max_k (cs_k-1)/k with v_rcp.
// Peak live ~45 VGPR -> __launch_bounds__(256,8): <=64 VGPR, no scratch,
// 8 waves/SIMD. LDS 4 KiB/wave transpose, XOR-swizzled (conflict-free).

#define T_DIM   262144
#define N_INST  16
#define B_DIM   8
#define NFRAME  (T_DIM / 64)          // 4096 frames per batch
#define WPB     4                     // independent waves per block

// ---------- serial bitonic (pass 1), compile-time direction ----------
template<int N, int K, int S>
__device__ __forceinline__ void bstage(float (&a)[N]) {
#pragma unroll
  for (int i = 0; i < N; ++i) {
    const int l = i ^ S;
    if (l > i) {
      const float x = a[i], y = a[l];
      const float hi = fmaxf(x, y), lo = fminf(x, y);
      const bool desc = ((i & K) == 0);
      a[i] = desc ? hi : lo;
      a[l] = desc ? lo : hi;
    }
  }
}

__device__ __forceinline__ void sort_desc16(float (&a)[16]) {
  bstage<16, 2, 1>(a);
  bstage<16, 4, 2>(a);  bstage<16, 4, 1>(a);
  bstage<16, 8, 4>(a);  bstage<16, 8, 2>(a);  bstage<16, 8, 1>(a);
  bstage<16, 16, 8>(a); bstage<16, 16, 4>(a); bstage<16, 16, 2>(a); bstage<16, 16, 1>(a);
}

// z sorted descending. tau = max_k (cs_k - 1)/k (exact max-identity;
// 1/(k+1) are compile-time literals).
__device__ __forceinline__ float tau16(const float (&z)[16]) {
  float cs = z[0];
  float tau = cs - 1.0f;
#pragma unroll
  for (int k = 1; k < 16; ++k) {
    cs += z[k];
    tau = fmaxf(tau, (cs - 1.0f) * (1.0f / (float)(k + 1)));
  }
  return tau;
}

// ---------- cross-lane helpers ----------
template<int X>  // XOR distance 1 or 2 (stays within 32-lane groups)
__device__ __forceinline__ float swz_xor(float x) {
  return __int_as_float(__builtin_amdgcn_ds_swizzle(
      __float_as_int(x), (X << 10) | 0x1f));  // BitMode: xor=X, and=0x1f
}

// ---------- pass-2 hybrid bitonic over e = q*16 + j (q = lane&3) ----------
// In-lane stage (S <= 8). Direction per element: desc = ((e&K)==0).
//   K<=8 : compile-time per j.  K==16: (q&1)==0.  K==32: (q&2)==0.  K==64: true.
template<int K, int S>
__device__ __forceinline__ void wstage(float (&a)[16], int q) {
#pragma unroll
  for (int j = 0; j < 16; ++j) {
    const int l = j ^ S;
    if (l > j) {
      const float hi = fmaxf(a[j], a[l]);
      const float lo = fminf(a[j], a[l]);
      bool desc;
      if constexpr (K <= 8)       desc = ((j & K) == 0);
      else if constexpr (K == 16) desc = ((q & 1) == 0);
      else if constexpr (K == 32) desc = ((q & 2) == 0);
      else                        desc = true;
      a[j] = desc ? hi : lo;
      a[l] = desc ? lo : hi;
    }
  }
}

// Cross-lane stage: S==16 -> partner lane^1 (e bit4 = q bit0);
//                   S==32 -> partner lane^2 (e bit5 = q bit1).
// keepmax = desc ^ bit_s, per-lane uniform.
template<int K, int S>
__device__ __forceinline__ void xlstage(float (&a)[16], int q) {
  const bool desc  = (K == 64) ? true : ((q & 2) == 0);   // K==32 or 64 only
  const bool bit_s = (S == 16) ? ((q & 1) != 0) : ((q & 2) != 0);
  const bool keepmax = desc ^ bit_s;
#pragma unroll
  for (int j = 0; j < 16; ++j) {
    const float y = swz_xor<(S == 16) ? 1 : 2>(a[j]);
    a[j] = keepmax ? fmaxf(a[j], y) : fminf(a[j], y);
  }
}

__device__ __forceinline__ void sort64_quad_desc(float (&w)[16], int q) {
  wstage<2, 1>(w, q);
  wstage<4, 2>(w, q);   wstage<4, 1>(w, q);
  wstage<8, 4>(w, q);   wstage<8, 2>(w, q);   wstage<8, 1>(w, q);
  wstage<16, 8>(w, q);  wstage<16, 4>(w, q);  wstage<16, 2>(w, q);  wstage<16, 1>(w, q);
  xlstage<32, 16>(w, q);
  wstage<32, 8>(w, q);  wstage<32, 4>(w, q);  wstage<32, 2>(w, q);  wstage<32, 1>(w, q);
  xlstage<64, 32>(w, q); xlstage<64, 16>(w, q);
  wstage<64, 8>(w, q);  wstage<64, 4>(w, q);  wstage<64, 2>(w, q);  wstage<64, 1>(w, q);
}

// lgkm-only fence (single-wave LDS slice; no block barrier needed).
__device__ __forceinline__ void lds_fence() {
  asm volatile("s_waitcnt lgkmcnt(0)" ::: "memory");
  __builtin_amdgcn_sched_barrier(0);
}

__global__ __launch_bounds__(256, 8) void seq_sparsemax_kernel(
    const float* __restrict__ in, float* __restrict__ out) {
  __shared__ float lds[WPB * N_INST * 64];  // 4 waves x 4 KiB

  const int lane = threadIdx.x & 63;
  const int wave = threadIdx.x >> 6;
  float* __restrict__ sp = &lds[wave * N_INST * 64];

  const int wid = blockIdx.x * WPB + wave;  // frame id, 0..32767
  const int b   = wid >> 12;                // / NFRAME
  const int fr  = wid & (NFRAME - 1);

  // ---- load: A[i] = in[b, i, fr*64 + lane]; coalesced 256B per inst ----
  const size_t base = (size_t)b * N_INST * T_DIM + (size_t)fr * 64 + lane;
  float A[N_INST];
#pragma unroll
  for (int i = 0; i < N_INST; ++i) A[i] = in[base + (size_t)i * T_DIM];

  // ---- pass 1 (lane-serial): sparsemax over the 16 insts of this column ----
  {
    float z[N_INST];
#pragma unroll
    for (int i = 0; i < N_INST; ++i) z[i] = A[i];
    sort_desc16(z);
    const float tau1 = tau16(z);
#pragma unroll
    for (int i = 0; i < N_INST; ++i) A[i] = fmaxf(A[i] - tau1, 0.0f);
  }

  // ---- transpose through 4 KiB LDS, XOR-swizzled ----
  // (inst i, time t) at float index i*64 + (t ^ ((i&7)<<2)).
  // writes: stride-1 per i (free); reads: 8 bank-quads fully covering
  // 32 banks, data-volume-bound.
#pragma unroll
  for (int i = 0; i < N_INST; ++i)
    sp[i * 64 + (lane ^ ((i & 7) << 2))] = A[i];
  lds_fence();

  const int r = lane >> 2;   // this quad's row (inst)
  const int q = lane & 3;    // position within quad
  float w[16];               // elements e = q*16 + j of row r
#pragma unroll
  for (int v = 0; v < 4; ++v) {
    const int u = (q * 16 + 4 * v) ^ ((r & 7) << 2);
    const float4 t = *reinterpret_cast<const float4*>(&sp[r * 64 + u]);
    w[4 * v + 0] = t.x; w[4 * v + 1] = t.y;
    w[4 * v + 2] = t.z; w[4 * v + 3] = t.w;
  }

  // ---- pass 2: quad-cooperative descending sort of the 64-row ----
  sort64_quad_desc(w, q);

  // ---- cumsum: in-lane prefix + exclusive quad offset (2 swizzles) ----
#pragma unroll
  for (int j = 1; j < 16; ++j) w[j] += w[j - 1];   // w[j] = in-lane prefix
  const float total   = w[15];
  const float u1      = swz_xor<1>(total);          // partner (q^1) total
  const float pairsum = total + u1;
  const float u2      = swz_xor<2>(pairsum);        // other pair's sum
  float excl = 0.0f;
  if (q & 1) excl += u1;
  if (q & 2) excl += u2;

  // ---- tau = max_e (cs_e - 1)/(e+1), e = q*16 + j ----
  const float qf = (float)(q * 16);
  float best = -__builtin_inff();
#pragma unroll
  for (int j = 0; j < 16; ++j) {
    const float cs = excl + w[j];
    const float kf = qf + (float)(j + 1);
    best = fmaxf(best, (cs - 1.0f) * __builtin_amdgcn_rcpf(kf));
  }
  best = fmaxf(best, swz_xor<1>(best));
  best = fmaxf(best, swz_xor<2>(best));   // all 4 lanes: tau of row r

  // ---- phase 3: pull tau_i from lane 4i; coalesced scalar stores ----
#pragma unroll
  for (int i = 0; i < N_INST; ++i) {
    const float ti = __int_as_float(
        __builtin_amdgcn_ds_bpermute((4 * i) << 2, __float_as_int(best)));
    out[base + (size_t)i * T_DIM] = fmaxf(A[i] - ti, 0.0f);
  }
}

extern "C" void kernel_launch(void* const* d_in, const int* in_sizes, int n_in,
                              void* d_out, int out_size, void* d_ws, size_t ws_size,
                              hipStream_t stream) {
  const float* in = (const float*)d_in[0];
  float* out = (float*)d_out;
  const int grid = B_DIM * NFRAME / WPB;  // 8192 blocks x 4 waves
  seq_sparsemax_kernel<<<grid, 64 * WPB, 0, stream>>>(in, out);
}